// Round 1
// baseline (633.613 us; speedup 1.0000x reference)
//
#include <hip/hip_runtime.h>
#include <hip/hip_bf16.h>

typedef __bf16 bf16;
typedef __bf16 bf16x8 __attribute__((ext_vector_type(8)));
typedef float floatx4 __attribute__((ext_vector_type(4)));

#define NB_ 8192
#define NU_ 32768

__device__ __forceinline__ float silu_f(float x) {
    return x / (1.0f + __expf(-x));
}

// ---------------- weight transpose + bf16 convert (7 x [512,512]) ----------------
__global__ void transpose_weights(const float* __restrict__ Wm, const float* __restrict__ Wu,
                                  const float* __restrict__ W1,
                                  bf16* __restrict__ WmT, bf16* __restrict__ WuT, bf16* __restrict__ W1T) {
    int z = blockIdx.z;
    const float* src; bf16* dst;
    if (z < 3)      { src = Wm + (size_t)z*262144;     dst = WmT + (size_t)z*262144; }
    else if (z < 6) { src = Wu + (size_t)(z-3)*262144; dst = WuT + (size_t)(z-3)*262144; }
    else            { src = W1;                        dst = W1T; }
    __shared__ float tile[32][33];
    int tx = threadIdx.x, ty = threadIdx.y;   // 32 x 8
    int x = blockIdx.x*32 + tx;
    int y0 = blockIdx.y*32;
    #pragma unroll
    for (int i = 0; i < 32; i += 8)
        tile[ty+i][tx] = src[(size_t)(y0+ty+i)*512 + x];
    __syncthreads();
    int xo = blockIdx.y*32 + tx;
    int yo0 = blockIdx.x*32;
    #pragma unroll
    for (int i = 0; i < 32; i += 8)
        dst[(size_t)(yo0+ty+i)*512 + xo] = (bf16)tile[tx][ty+i];
}

// ---------------- ebias[l][t][c] = sum_e edge_emb[t][e] * We[l][e][c] ----------------
__global__ void ebias_kernel(const float* __restrict__ edge_emb, const float* __restrict__ We,
                             float* __restrict__ ebias) {
    int gid = blockIdx.x*256 + threadIdx.x;   // 3*2*512 = 3072
    if (gid >= 3072) return;
    int l = gid >> 10, t = (gid >> 9) & 1, c = gid & 511;
    float s = 0.0f;
    #pragma unroll 8
    for (int e = 0; e < 64; e++)
        s += edge_emb[t*64 + e] * We[(size_t)(l*64 + e)*512 + c];
    ebias[gid] = s;
}

// ---------------- per-block setup: Zp, Zb0, Zb, h (fp32 + bf16) ----------------
__global__ void setup_kernel(const float* __restrict__ Z, const float* __restrict__ noise,
                             const int* __restrict__ noise_level, const float* __restrict__ sigmas,
                             const int* __restrict__ Aarr, const int* __restrict__ posa,
                             const int* __restrict__ Barr,
                             const float* __restrict__ atom_emb, const float* __restrict__ pos_emb,
                             const float* __restrict__ block_emb,
                             float* __restrict__ Zp, float* __restrict__ Zb0, float* __restrict__ Zb,
                             float* __restrict__ hf, bf16* __restrict__ hb) {
    int b = blockIdx.x;              // 8192 blocks, 128 threads
    int tid = threadIdx.x;
    int g = b >> 10;
    __shared__ float zsh[12];
    if (tid < 12) {
        float sig = sigmas[noise_level[g]];
        int idx = b*12 + tid;
        float zp = Z[idx] + noise[idx]*sig;
        Zp[idx] = zp;
        zsh[tid] = zp;
    }
    __syncthreads();
    if (tid < 3) {
        float v = 0.25f*(zsh[tid] + zsh[3+tid] + zsh[6+tid] + zsh[9+tid]);
        Zb0[b*3+tid] = v; Zb[b*3+tid] = v;
    }
    int ai[4], pi[4];
    #pragma unroll
    for (int a = 0; a < 4; a++) { ai[a] = Aarr[b*4+a]*512; pi[a] = posa[b*4+a]*512; }
    int bb = Barr[b]*512;
    for (int c = tid; c < 512; c += 128) {
        float s = 0.0f;
        #pragma unroll
        for (int a = 0; a < 4; a++) s += atom_emb[ai[a]+c] + pos_emb[pi[a]+c];
        s = 0.25f*s + block_emb[bb+c];
        hf[(size_t)b*512+c] = s;
        hb[(size_t)b*512+c] = (bf16)s;
    }
}

// ---------------- KNN: one wave per dst block; 9 intra + 9 inter ----------------
__global__ __launch_bounds__(256) void knn_kernel(const float* __restrict__ Zp,
                                                  const int* __restrict__ seg,
                                                  int* __restrict__ nbr) {
    int wid = threadIdx.x >> 6;
    int lane = threadIdx.x & 63;
    int r = blockIdx.x*4 + wid;     // dst block (global)
    int g = r >> 10;
    int il = r & 1023;
    int segr = seg[r];
    float za[4][3];
    #pragma unroll
    for (int a = 0; a < 4; a++)
        #pragma unroll
        for (int d = 0; d < 3; d++)
            za[a][d] = Zp[r*12 + a*3 + d];
    float dist[16];
    unsigned smask = 0;
    int base = g << 10;
    #pragma unroll
    for (int t = 0; t < 16; t++) {
        int j = t*64 + lane;
        int jb = base + j;
        const float4* p = (const float4*)(Zp + (size_t)jb*12);
        float4 v0 = p[0], v1 = p[1], v2 = p[2];
        float bx[4] = {v0.x, v0.w, v1.z, v2.y};
        float by[4] = {v0.y, v1.x, v1.w, v2.z};
        float bz[4] = {v0.z, v1.y, v2.x, v2.w};
        float dm = 3.0e38f;
        #pragma unroll
        for (int a = 0; a < 4; a++) {
            #pragma unroll
            for (int bq = 0; bq < 4; bq++) {
                float dx = za[a][0]-bx[bq], dy = za[a][1]-by[bq], dz = za[a][2]-bz[bq];
                float dd = dx*dx + dy*dy + dz*dz;
                dm = fminf(dm, dd);
            }
        }
        dist[t] = dm;
        if (seg[jb] == segr) smask |= (1u << t);
    }
    unsigned removed = 0;
    for (int phase = 0; phase < 2; phase++) {
        for (int it = 0; it < 9; it++) {
            float bestd = 3.0e38f; int bestt = 0;
            #pragma unroll
            for (int t = 0; t < 16; t++) {
                int j = t*64 + lane;
                bool ok = (phase == 0) ? (((smask>>t)&1u) && (j != il))
                                       : (!((smask>>t)&1u));
                ok = ok && !((removed>>t)&1u);
                float dv = ok ? dist[t] : 1.0e9f;
                if (dv < bestd) { bestd = dv; bestt = t; }
            }
            int bestj = bestt*64 + lane;
            unsigned long long key =
                (((unsigned long long)__float_as_uint(bestd)) << 32) | (unsigned)bestj;
            #pragma unroll
            for (int off = 32; off >= 1; off >>= 1) {
                unsigned long long o = __shfl_xor(key, off, 64);
                if (o < key) key = o;
            }
            int jwin = (int)(key & 0xffffffffu);
            if (lane == 0) nbr[r*18 + phase*9 + it] = base + jwin;
            if ((jwin & 63) == lane) removed |= (1u << (jwin >> 6));
        }
    }
}

// ---------------- bf16 MFMA GEMM: C[8192,512] = A[8192,512] @ BT[512,512]^T ----------------
// mode 0: C = acc (P)
// mode 1: hf += silu(acc); hb = bf16(hf)   (U-GEMM, h update)
// mode 2: C = silu(acc + b1[col])          (energy head)
__global__ __launch_bounds__(256) void gemm_kernel(const bf16* __restrict__ A, const bf16* __restrict__ BT,
                                                   float* __restrict__ C, float* __restrict__ hf,
                                                   bf16* __restrict__ hb, const float* __restrict__ b1,
                                                   int mode) {
    int bid = blockIdx.x;
    int mt = bid & 63, nt = bid >> 6;
    int m0 = mt*128, n0 = nt*128;
    int tid = threadIdx.x, lane = tid & 63, wid = tid >> 6;
    int wm = wid & 1, wn = wid >> 1;
    int lm = lane & 15, q = lane >> 4;
    __shared__ alignas(16) bf16 sA[128*40];
    __shared__ alignas(16) bf16 sB[128*40];
    floatx4 zv = {0.0f, 0.0f, 0.0f, 0.0f};
    floatx4 acc[4][4];
    #pragma unroll
    for (int i = 0; i < 4; i++)
        #pragma unroll
        for (int j = 0; j < 4; j++) acc[i][j] = zv;
    for (int k0 = 0; k0 < 512; k0 += 32) {
        #pragma unroll
        for (int it = 0; it < 2; it++) {
            int idx = tid + it*256;       // 512 16B-chunks per tile
            int row = idx >> 2, qt = idx & 3;
            *(int4*)(sA + row*40 + qt*8) = *(const int4*)(A + (size_t)(m0+row)*512 + k0 + qt*8);
            *(int4*)(sB + row*40 + qt*8) = *(const int4*)(BT + (size_t)(n0+row)*512 + k0 + qt*8);
        }
        __syncthreads();
        bf16x8 af[4], bfr[4];
        #pragma unroll
        for (int tm = 0; tm < 4; tm++)
            af[tm] = *(const bf16x8*)(sA + (wm*64 + tm*16 + lm)*40 + q*8);
        #pragma unroll
        for (int tn = 0; tn < 4; tn++)
            bfr[tn] = *(const bf16x8*)(sB + (wn*64 + tn*16 + lm)*40 + q*8);
        #pragma unroll
        for (int tm = 0; tm < 4; tm++)
            #pragma unroll
            for (int tn = 0; tn < 4; tn++)
                acc[tm][tn] = __builtin_amdgcn_mfma_f32_16x16x32_bf16(af[tm], bfr[tn], acc[tm][tn], 0, 0, 0);
        __syncthreads();
    }
    #pragma unroll
    for (int tm = 0; tm < 4; tm++) {
        #pragma unroll
        for (int tn = 0; tn < 4; tn++) {
            #pragma unroll
            for (int rr = 0; rr < 4; rr++) {
                int row = m0 + wm*64 + tm*16 + q*4 + rr;
                int col = n0 + wn*64 + tn*16 + lm;
                size_t o = (size_t)row*512 + col;
                float v = acc[tm][tn][rr];
                if (mode == 0) {
                    C[o] = v;
                } else if (mode == 1) {
                    float nh = hf[o] + silu_f(v);
                    hf[o] = nh;
                    hb[o] = (bf16)nh;
                } else {
                    C[o] = silu_f(v + b1[col]);
                }
            }
        }
    }
}

// ---------------- edge aggregation: msum, coef, zacc per dst block ----------------
__global__ __launch_bounds__(256) void edge_kernel(const float* __restrict__ P, const float* __restrict__ ebias,
                                                   const float* __restrict__ wz, const float* __restrict__ Zb,
                                                   const int* __restrict__ nbr, bf16* __restrict__ msum,
                                                   float* __restrict__ zacc) {
    int b = blockIdx.x, tid = threadIdx.x;
    int c0 = tid, c1 = tid + 256;
    int lane = tid & 63, wid = tid >> 6;
    __shared__ int srcs[18];
    __shared__ float red[18][4];
    __shared__ float term[18][3];
    if (tid < 18) srcs[tid] = nbr[b*18 + tid];
    __syncthreads();
    float pd0 = P[(size_t)b*512 + c0], pd1 = P[(size_t)b*512 + c1];
    float eb00 = ebias[c0],       eb01 = ebias[c1];
    float eb10 = ebias[512 + c0], eb11 = ebias[512 + c1];
    float w0 = wz[c0], w1 = wz[c1];
    float ms0 = 0.0f, ms1 = 0.0f;
    float pdot[18];
    #pragma unroll
    for (int e = 0; e < 18; e++) {
        int s = srcs[e];
        float ba = (e < 9) ? eb00 : eb10;
        float bb = (e < 9) ? eb01 : eb11;
        float x0 = P[(size_t)s*512 + c0] + pd0 + ba;
        float x1 = P[(size_t)s*512 + c1] + pd1 + bb;
        float m0 = silu_f(x0), m1 = silu_f(x1);
        ms0 += m0; ms1 += m1;
        pdot[e] = m0*w0 + m1*w1;
    }
    msum[(size_t)b*512 + c0] = (bf16)ms0;
    msum[(size_t)b*512 + c1] = (bf16)ms1;
    #pragma unroll
    for (int e = 0; e < 18; e++) {
        float v = pdot[e];
        #pragma unroll
        for (int off = 32; off >= 1; off >>= 1) v += __shfl_xor(v, off, 64);
        if (lane == 0) red[e][wid] = v;
    }
    __syncthreads();
    if (tid < 18) {
        float dot = red[tid][0] + red[tid][1] + red[tid][2] + red[tid][3];
        float coef = tanhf(dot);
        int s = srcs[tid];
        #pragma unroll
        for (int d = 0; d < 3; d++)
            term[tid][d] = (Zb[s*3 + d] - Zb[b*3 + d]) * coef;
    }
    __syncthreads();
    if (tid < 3) {
        float s = 0.0f;
        #pragma unroll
        for (int e = 0; e < 18; e++) s += term[e][tid];
        zacc[b*3 + tid] = s;
    }
}

__global__ void zb_apply(float* __restrict__ Zb, const float* __restrict__ zacc) {
    int i = blockIdx.x*256 + threadIdx.x;
    if (i < NB_*3) Zb[i] += zacc[i] * (1.0f/18.0f);
}

__global__ void silu_bf16_kernel(const float* __restrict__ h, bf16* __restrict__ sh) {
    #pragma unroll
    for (int k = 0; k < 4; k++) {
        int idx = blockIdx.x*1024 + k*256 + threadIdx.x;
        sh[idx] = (bf16)silu_f(h[idx]);
    }
}

__global__ __launch_bounds__(256) void edot_kernel(const float* __restrict__ t1, const float* __restrict__ W2,
                                                   float* __restrict__ eblk) {
    int wid = threadIdx.x >> 6, lane = threadIdx.x & 63;
    int b = blockIdx.x*4 + wid;
    float s = 0.0f;
    #pragma unroll
    for (int k = 0; k < 8; k++) {
        int c = k*64 + lane;
        s += t1[(size_t)b*512 + c] * W2[c];
    }
    #pragma unroll
    for (int off = 32; off >= 1; off >>= 1) s += __shfl_xor(s, off, 64);
    if (lane == 0) eblk[b] = s;
}

__global__ void energy_kernel(const float* __restrict__ eblk, float* __restrict__ out_e) {
    int g = blockIdx.x, tid = threadIdx.x;
    __shared__ float red[256];
    float s = 0.0f;
    #pragma unroll
    for (int k = 0; k < 4; k++) s += eblk[g*1024 + k*256 + tid];
    red[tid] = s; __syncthreads();
    for (int st = 128; st > 0; st >>= 1) {
        if (tid < st) red[tid] += red[tid+st];
        __syncthreads();
    }
    if (tid == 0) out_e[g] = red[0];
}

__global__ void graphrepr_kernel(const float* __restrict__ h, float* __restrict__ out_gr) {
    int g = blockIdx.x >> 1;
    int c = (blockIdx.x & 1)*256 + threadIdx.x;
    float s = 0.0f;
    for (int bb = 0; bb < 1024; bb++) s += h[(size_t)((g<<10)+bb)*512 + c];
    out_gr[g*512 + c] = s;
}

__global__ void prednoise_loss_kernel(const float* __restrict__ Zb, const float* __restrict__ Zb0,
                                      const float* __restrict__ noise,
                                      float* __restrict__ out_pn, float* __restrict__ out_loss) {
    int u = blockIdx.x*256 + threadIdx.x;
    int b = u >> 2;
    float per = 0.0f;
    #pragma unroll
    for (int d = 0; d < 3; d++) {
        float dv = Zb[b*3+d] - Zb0[b*3+d];
        out_pn[u*3+d] = dv;
        float e = dv - noise[u*3+d];
        per += e*e;
    }
    __shared__ float red[256];
    red[threadIdx.x] = per; __syncthreads();
    for (int st = 128; st > 0; st >>= 1) {
        if (threadIdx.x < st) red[threadIdx.x] += red[threadIdx.x+st];
        __syncthreads();
    }
    if (threadIdx.x == 0) atomicAdd(out_loss, red[0] * (1.0f/16.0f));
}

__global__ void unitrepr_kernel(const int* __restrict__ Aarr, const int* __restrict__ posa,
                                const int* __restrict__ Barr,
                                const float* __restrict__ atom_emb, const float* __restrict__ pos_emb,
                                const float* __restrict__ block_emb,
                                const float* __restrict__ h, float* __restrict__ out_ur) {
    #pragma unroll
    for (int k = 0; k < 4; k++) {
        int idx = blockIdx.x*1024 + k*256 + threadIdx.x;
        int u = idx >> 9, c = idx & 511, b = u >> 2;
        out_ur[idx] = atom_emb[Aarr[u]*512+c] + pos_emb[posa[u]*512+c]
                    + block_emb[Barr[b]*512+c] + h[(size_t)b*512+c];
    }
}

extern "C" void kernel_launch(void* const* d_in, const int* in_sizes, int n_in,
                              void* d_out, int out_size, void* d_ws, size_t ws_size,
                              hipStream_t stream) {
    const float* Z         = (const float*)d_in[0];
    const int*   B         = (const int*)d_in[1];
    const int*   A         = (const int*)d_in[2];
    const int*   ap        = (const int*)d_in[3];
    const int*   seg       = (const int*)d_in[6];
    const float* noise     = (const float*)d_in[7];
    const int*   nl        = (const int*)d_in[8];
    const float* sig       = (const float*)d_in[9];
    const float* atom_emb  = (const float*)d_in[10];
    const float* pos_emb   = (const float*)d_in[11];
    const float* block_emb = (const float*)d_in[12];
    const float* edge_emb  = (const float*)d_in[13];
    const float* Wm        = (const float*)d_in[14];
    const float* We        = (const float*)d_in[15];
    const float* Wu        = (const float*)d_in[16];
    const float* wz        = (const float*)d_in[17];
    const float* W1        = (const float*)d_in[18];
    const float* b1        = (const float*)d_in[19];
    const float* W2        = (const float*)d_in[20];
    (void)in_sizes; (void)n_in; (void)d_ws; (void)ws_size; (void)out_size;

    float* out = (float*)d_out;
    const size_t o1 = 8, o2 = 98312, o3 = 16875528, o4 = 21069832, o5 = 21073928;
    float* out_e    = out;
    float* out_pn   = out + o1;
    float* out_ur   = out + o2;
    float* hf       = out + o3;   // block_repr == final h (fp32), updated in place
    float* out_gr   = out + o4;
    float* out_loss = out + o5;

    // scratch arena inside the unit_repr output region (67 MB); unit_repr written last
    char* arena = (char*)(out + o2);
    float* P    = (float*)(arena);                 // 16 MB (also t1 in energy head)
    bf16*  msum = (bf16*)(arena + 16777216);       // 8 MB
    bf16*  sh   = (bf16*)(arena + 25165824);       // 8 MB
    bf16*  hb   = (bf16*)(arena + 33554432);       // 8 MB
    float* Zp   = (float*)(arena + 41943040);
    float* Zb0  = (float*)(arena + 42336256);
    float* Zb   = (float*)(arena + 42434560);
    float* zacc = (float*)(arena + 42532864);
    int*   nbr  = (int*)  (arena + 42631168);
    bf16*  WmT  = (bf16*) (arena + 43220992);
    bf16*  WuT  = (bf16*) (arena + 44793856);
    bf16*  W1T  = (bf16*) (arena + 46366720);
    float* ebias= (float*)(arena + 46891008);
    float* eblk = (float*)(arena + 46903296);

    hipMemsetAsync(out_loss, 0, 4, stream);
    transpose_weights<<<dim3(16,16,7), dim3(32,8), 0, stream>>>(Wm, Wu, W1, WmT, WuT, W1T);
    ebias_kernel<<<12, 256, 0, stream>>>(edge_emb, We, ebias);
    setup_kernel<<<8192, 128, 0, stream>>>(Z, noise, nl, sig, A, ap, B,
                                           atom_emb, pos_emb, block_emb,
                                           Zp, Zb0, Zb, hf, hb);
    knn_kernel<<<2048, 256, 0, stream>>>(Zp, seg, nbr);
    for (int l = 0; l < 3; l++) {
        gemm_kernel<<<256, 256, 0, stream>>>(hb, WmT + (size_t)l*262144, P, nullptr, nullptr, nullptr, 0);
        edge_kernel<<<8192, 256, 0, stream>>>(P, ebias + l*1024, wz + l*512, Zb, nbr, msum, zacc);
        gemm_kernel<<<256, 256, 0, stream>>>(msum, WuT + (size_t)l*262144, nullptr, hf, hb, nullptr, 1);
        zb_apply<<<96, 256, 0, stream>>>(Zb, zacc);
    }
    silu_bf16_kernel<<<4096, 256, 0, stream>>>(hf, sh);
    gemm_kernel<<<256, 256, 0, stream>>>(sh, W1T, P, nullptr, nullptr, b1, 2);
    edot_kernel<<<2048, 256, 0, stream>>>(P, W2, eblk);
    energy_kernel<<<8, 256, 0, stream>>>(eblk, out_e);
    graphrepr_kernel<<<16, 256, 0, stream>>>(hf, out_gr);
    prednoise_loss_kernel<<<128, 256, 0, stream>>>(Zb, Zb0, noise, out_pn, out_loss);
    // unit_repr last: overwrites the scratch arena
    unitrepr_kernel<<<16384, 256, 0, stream>>>(A, ap, B, atom_emb, pos_emb, block_emb, hf, out_ur);
}

// Round 2
// 528.920 us; speedup vs baseline: 1.1979x; 1.1979x over previous
//
#include <hip/hip_runtime.h>
#include <hip/hip_bf16.h>

typedef __bf16 bf16;
typedef __bf16 bf16x2 __attribute__((ext_vector_type(2)));
typedef __bf16 bf16x8 __attribute__((ext_vector_type(8)));
typedef float floatx4 __attribute__((ext_vector_type(4)));

#define NB_ 8192
#define NU_ 32768

__device__ __forceinline__ float silu_f(float x) {
    // x * rcp(1+exp(-x)) : v_rcp_f32 approx instead of the IEEE div sequence
    float e = __expf(-x);
    return x * __builtin_amdgcn_rcpf(1.0f + e);
}

// ---------------- weight transpose + bf16 convert (7 x [512,512]) ----------------
__global__ void transpose_weights(const float* __restrict__ Wm, const float* __restrict__ Wu,
                                  const float* __restrict__ W1,
                                  bf16* __restrict__ WmT, bf16* __restrict__ WuT, bf16* __restrict__ W1T) {
    int z = blockIdx.z;
    const float* src; bf16* dst;
    if (z < 3)      { src = Wm + (size_t)z*262144;     dst = WmT + (size_t)z*262144; }
    else if (z < 6) { src = Wu + (size_t)(z-3)*262144; dst = WuT + (size_t)(z-3)*262144; }
    else            { src = W1;                        dst = W1T; }
    __shared__ float tile[32][33];
    int tx = threadIdx.x, ty = threadIdx.y;   // 32 x 8
    int x = blockIdx.x*32 + tx;
    int y0 = blockIdx.y*32;
    #pragma unroll
    for (int i = 0; i < 32; i += 8)
        tile[ty+i][tx] = src[(size_t)(y0+ty+i)*512 + x];
    __syncthreads();
    int xo = blockIdx.y*32 + tx;
    int yo0 = blockIdx.x*32;
    #pragma unroll
    for (int i = 0; i < 32; i += 8)
        dst[(size_t)(yo0+ty+i)*512 + xo] = (bf16)tile[tx][ty+i];
}

// ---------------- ebias[l][t][c] = sum_e edge_emb[t][e] * We[l][e][c] ----------------
__global__ void ebias_kernel(const float* __restrict__ edge_emb, const float* __restrict__ We,
                             float* __restrict__ ebias) {
    int gid = blockIdx.x*256 + threadIdx.x;   // 3*2*512 = 3072
    if (gid >= 3072) return;
    int l = gid >> 10, t = (gid >> 9) & 1, c = gid & 511;
    float s = 0.0f;
    #pragma unroll 8
    for (int e = 0; e < 64; e++)
        s += edge_emb[t*64 + e] * We[(size_t)(l*64 + e)*512 + c];
    ebias[gid] = s;
}

// ---------------- per-block setup: Zp, Zb0, Zb, h (fp32 + bf16) ----------------
__global__ void setup_kernel(const float* __restrict__ Z, const float* __restrict__ noise,
                             const int* __restrict__ noise_level, const float* __restrict__ sigmas,
                             const int* __restrict__ Aarr, const int* __restrict__ posa,
                             const int* __restrict__ Barr,
                             const float* __restrict__ atom_emb, const float* __restrict__ pos_emb,
                             const float* __restrict__ block_emb,
                             float* __restrict__ Zp, float* __restrict__ Zb0, float* __restrict__ Zb,
                             float* __restrict__ hf, bf16* __restrict__ hb) {
    int b = blockIdx.x;              // 8192 blocks, 128 threads
    int tid = threadIdx.x;
    int g = b >> 10;
    __shared__ float zsh[12];
    if (tid < 12) {
        float sig = sigmas[noise_level[g]];
        int idx = b*12 + tid;
        float zp = Z[idx] + noise[idx]*sig;
        Zp[idx] = zp;
        zsh[tid] = zp;
    }
    __syncthreads();
    if (tid < 3) {
        float v = 0.25f*(zsh[tid] + zsh[3+tid] + zsh[6+tid] + zsh[9+tid]);
        Zb0[b*3+tid] = v; Zb[b*3+tid] = v;
    }
    int ai[4], pi[4];
    #pragma unroll
    for (int a = 0; a < 4; a++) { ai[a] = Aarr[b*4+a]*512; pi[a] = posa[b*4+a]*512; }
    int bb = Barr[b]*512;
    for (int c = tid; c < 512; c += 128) {
        float s = 0.0f;
        #pragma unroll
        for (int a = 0; a < 4; a++) s += atom_emb[ai[a]+c] + pos_emb[pi[a]+c];
        s = 0.25f*s + block_emb[bb+c];
        hf[(size_t)b*512+c] = s;
        hb[(size_t)b*512+c] = (bf16)s;
    }
}

// ---------------- KNN: one wave per dst block; 9 intra + 9 inter ----------------
__global__ __launch_bounds__(256) void knn_kernel(const float* __restrict__ Zp,
                                                  const int* __restrict__ seg,
                                                  int* __restrict__ nbr) {
    int wid = threadIdx.x >> 6;
    int lane = threadIdx.x & 63;
    int r = blockIdx.x*4 + wid;     // dst block (global)
    int g = r >> 10;
    int il = r & 1023;
    int segr = seg[r];
    float za[4][3];
    #pragma unroll
    for (int a = 0; a < 4; a++)
        #pragma unroll
        for (int d = 0; d < 3; d++)
            za[a][d] = Zp[r*12 + a*3 + d];
    float dist[16];
    unsigned smask = 0;
    int base = g << 10;
    #pragma unroll
    for (int t = 0; t < 16; t++) {
        int j = t*64 + lane;
        int jb = base + j;
        const float4* p = (const float4*)(Zp + (size_t)jb*12);
        float4 v0 = p[0], v1 = p[1], v2 = p[2];
        float bx[4] = {v0.x, v0.w, v1.z, v2.y};
        float by[4] = {v0.y, v1.x, v1.w, v2.z};
        float bz[4] = {v0.z, v1.y, v2.x, v2.w};
        float dm = 3.0e38f;
        #pragma unroll
        for (int a = 0; a < 4; a++) {
            #pragma unroll
            for (int bq = 0; bq < 4; bq++) {
                float dx = za[a][0]-bx[bq], dy = za[a][1]-by[bq], dz = za[a][2]-bz[bq];
                float dd = dx*dx + dy*dy + dz*dz;
                dm = fminf(dm, dd);
            }
        }
        dist[t] = dm;
        if (seg[jb] == segr) smask |= (1u << t);
    }
    unsigned removed = 0;
    for (int phase = 0; phase < 2; phase++) {
        for (int it = 0; it < 9; it++) {
            float bestd = 3.0e38f; int bestt = 0;
            #pragma unroll
            for (int t = 0; t < 16; t++) {
                int j = t*64 + lane;
                bool ok = (phase == 0) ? (((smask>>t)&1u) && (j != il))
                                       : (!((smask>>t)&1u));
                ok = ok && !((removed>>t)&1u);
                float dv = ok ? dist[t] : 1.0e9f;
                if (dv < bestd) { bestd = dv; bestt = t; }
            }
            int bestj = bestt*64 + lane;
            unsigned long long key =
                (((unsigned long long)__float_as_uint(bestd)) << 32) | (unsigned)bestj;
            #pragma unroll
            for (int off = 32; off >= 1; off >>= 1) {
                unsigned long long o = __shfl_xor(key, off, 64);
                if (o < key) key = o;
            }
            int jwin = (int)(key & 0xffffffffu);
            if (lane == 0) nbr[r*18 + phase*9 + it] = base + jwin;
            if ((jwin & 63) == lane) removed |= (1u << (jwin >> 6));
        }
    }
}

// ---------------- bf16 MFMA GEMM: [8192,512] @ BT[512,512]^T, tile 128Mx64N ----------------
// grid 512 (64 M-tiles x 8 N-tiles) -> 2 WG/CU
// mode 0: C = acc (P)
// mode 1: hf += silu(acc); hb = bf16(hf); if (shp) shp = bf16(silu(hf))
// mode 2: t = silu(acc + b1[col]); eblk[row] += t . W2   (fused energy head)
__global__ __launch_bounds__(256) void gemm_kernel(const bf16* __restrict__ A, const bf16* __restrict__ BT,
                                                   float* __restrict__ C, float* __restrict__ hf,
                                                   bf16* __restrict__ hb, bf16* __restrict__ shp,
                                                   const float* __restrict__ b1,
                                                   const float* __restrict__ W2,
                                                   float* __restrict__ eblk,
                                                   int mode) {
    int bid = blockIdx.x;
    int mt = bid & 63, nt = bid >> 6;        // 64 x 8
    int m0 = mt*128, n0 = nt*64;
    int tid = threadIdx.x, lane = tid & 63, wid = tid >> 6;
    int wm = wid & 1, wn = wid >> 1;         // 2 x 2 waves: 64 rows x 32 cols each
    int lm = lane & 15, q = lane >> 4;
    __shared__ alignas(16) bf16 sA[128*40];
    __shared__ alignas(16) bf16 sB[64*40];
    floatx4 zv = {0.0f, 0.0f, 0.0f, 0.0f};
    floatx4 acc[4][2];
    #pragma unroll
    for (int i = 0; i < 4; i++)
        #pragma unroll
        for (int j = 0; j < 2; j++) acc[i][j] = zv;
    for (int k0 = 0; k0 < 512; k0 += 32) {
        #pragma unroll
        for (int it = 0; it < 2; it++) {
            int idx = tid + it*256;          // 512 16B chunks for A
            int row = idx >> 2, qt = idx & 3;
            *(int4*)(sA + row*40 + qt*8) = *(const int4*)(A + (size_t)(m0+row)*512 + k0 + qt*8);
        }
        {
            int row = tid >> 2, qt = tid & 3; // 256 16B chunks for B
            *(int4*)(sB + row*40 + qt*8) = *(const int4*)(BT + (size_t)(n0+row)*512 + k0 + qt*8);
        }
        __syncthreads();
        bf16x8 af[4], bfr[2];
        #pragma unroll
        for (int tm = 0; tm < 4; tm++)
            af[tm] = *(const bf16x8*)(sA + (wm*64 + tm*16 + lm)*40 + q*8);
        #pragma unroll
        for (int tn = 0; tn < 2; tn++)
            bfr[tn] = *(const bf16x8*)(sB + (wn*32 + tn*16 + lm)*40 + q*8);
        #pragma unroll
        for (int tm = 0; tm < 4; tm++)
            #pragma unroll
            for (int tn = 0; tn < 2; tn++)
                acc[tm][tn] = __builtin_amdgcn_mfma_f32_16x16x32_bf16(af[tm], bfr[tn], acc[tm][tn], 0, 0, 0);
        __syncthreads();
    }
    if (mode == 2) {
        #pragma unroll
        for (int tm = 0; tm < 4; tm++) {
            #pragma unroll
            for (int rr = 0; rr < 4; rr++) {
                float part = 0.0f;
                #pragma unroll
                for (int tn = 0; tn < 2; tn++) {
                    int col = n0 + wn*32 + tn*16 + lm;
                    float t = silu_f(acc[tm][tn][rr] + b1[col]);
                    part += t * W2[col];
                }
                part += __shfl_xor(part, 1, 64);
                part += __shfl_xor(part, 2, 64);
                part += __shfl_xor(part, 4, 64);
                part += __shfl_xor(part, 8, 64);
                if (lm == 0) {
                    int row = m0 + wm*64 + tm*16 + q*4 + rr;
                    atomicAdd(&eblk[row], part);
                }
            }
        }
        return;
    }
    #pragma unroll
    for (int tm = 0; tm < 4; tm++) {
        #pragma unroll
        for (int tn = 0; tn < 2; tn++) {
            #pragma unroll
            for (int rr = 0; rr < 4; rr++) {
                int row = m0 + wm*64 + tm*16 + q*4 + rr;
                int col = n0 + wn*32 + tn*16 + lm;
                size_t o = (size_t)row*512 + col;
                float v = acc[tm][tn][rr];
                if (mode == 0) {
                    C[o] = v;
                } else {
                    float nh = hf[o] + silu_f(v);
                    hf[o] = nh;
                    hb[o] = (bf16)nh;
                    if (shp) shp[o] = (bf16)silu_f(nh);
                }
            }
        }
    }
}

// ---------------- edge aggregation: msum, coef, zacc per dst block ----------------
__global__ __launch_bounds__(256) void edge_kernel(const float* __restrict__ P, const float* __restrict__ ebias,
                                                   const float* __restrict__ wz, const float* __restrict__ Zb,
                                                   const int* __restrict__ nbr, bf16* __restrict__ msum,
                                                   float* __restrict__ zacc) {
    int b = blockIdx.x, tid = threadIdx.x;
    int c0 = 2*tid;                               // adjacent channels -> float2 loads
    int lane = tid & 63, wid = tid >> 6;
    __shared__ int srcs[18];
    __shared__ float red[18][4];
    __shared__ float term[18][3];
    if (tid < 18) srcs[tid] = nbr[b*18 + tid];
    __syncthreads();
    float2 pd  = *(const float2*)(P + (size_t)b*512 + c0);
    float2 eb0 = *(const float2*)(ebias + c0);
    float2 eb1 = *(const float2*)(ebias + 512 + c0);
    float2 w   = *(const float2*)(wz + c0);
    float ms0 = 0.0f, ms1 = 0.0f;
    float pdot[18];
    #pragma unroll
    for (int e = 0; e < 18; e++) {
        int s = srcs[e];
        float2 pv = *(const float2*)(P + (size_t)s*512 + c0);
        float ba = (e < 9) ? eb0.x : eb1.x;
        float bb = (e < 9) ? eb0.y : eb1.y;
        float m0 = silu_f(pv.x + pd.x + ba);
        float m1 = silu_f(pv.y + pd.y + bb);
        ms0 += m0; ms1 += m1;
        pdot[e] = m0*w.x + m1*w.y;
    }
    bf16x2 mp = { (bf16)ms0, (bf16)ms1 };
    *(bf16x2*)(msum + (size_t)b*512 + c0) = mp;
    #pragma unroll
    for (int e = 0; e < 18; e++) {
        float v = pdot[e];
        #pragma unroll
        for (int off = 32; off >= 1; off >>= 1) v += __shfl_xor(v, off, 64);
        if (lane == 0) red[e][wid] = v;
    }
    __syncthreads();
    if (tid < 18) {
        float dot = red[tid][0] + red[tid][1] + red[tid][2] + red[tid][3];
        float coef = tanhf(dot);
        int s = srcs[tid];
        #pragma unroll
        for (int d = 0; d < 3; d++)
            term[tid][d] = (Zb[s*3 + d] - Zb[b*3 + d]) * coef;
    }
    __syncthreads();
    if (tid < 3) {
        float s = 0.0f;
        #pragma unroll
        for (int e = 0; e < 18; e++) s += term[e][tid];
        zacc[b*3 + tid] = s;
    }
}

__global__ void zb_apply(float* __restrict__ Zb, const float* __restrict__ zacc) {
    int i = blockIdx.x*256 + threadIdx.x;
    if (i < NB_*3) Zb[i] += zacc[i] * (1.0f/18.0f);
}

__global__ void energy_kernel(const float* __restrict__ eblk, float* __restrict__ out_e) {
    int g = blockIdx.x, tid = threadIdx.x;
    __shared__ float red[256];
    float s = 0.0f;
    #pragma unroll
    for (int k = 0; k < 4; k++) s += eblk[g*1024 + k*256 + tid];
    red[tid] = s; __syncthreads();
    for (int st = 128; st > 0; st >>= 1) {
        if (tid < st) red[tid] += red[tid+st];
        __syncthreads();
    }
    if (tid == 0) out_e[g] = red[0];
}

// 256 WGs: (g, 64-block chunk, col half) -> atomicAdd partials
__global__ void graphrepr_kernel(const float* __restrict__ h, float* __restrict__ out_gr) {
    int g = blockIdx.x >> 5;
    int rc = (blockIdx.x >> 1) & 15;
    int ch = blockIdx.x & 1;
    int c = ch*256 + threadIdx.x;
    int b0 = (g << 10) + rc*64;
    float s = 0.0f;
    for (int i = 0; i < 64; i++) s += h[(size_t)(b0+i)*512 + c];
    atomicAdd(&out_gr[g*512 + c], s);
}

__global__ void prednoise_loss_kernel(const float* __restrict__ Zb, const float* __restrict__ Zb0,
                                      const float* __restrict__ noise,
                                      float* __restrict__ out_pn, float* __restrict__ out_loss) {
    int u = blockIdx.x*256 + threadIdx.x;
    int b = u >> 2;
    float per = 0.0f;
    #pragma unroll
    for (int d = 0; d < 3; d++) {
        float dv = Zb[b*3+d] - Zb0[b*3+d];
        out_pn[u*3+d] = dv;
        float e = dv - noise[u*3+d];
        per += e*e;
    }
    __shared__ float red[256];
    red[threadIdx.x] = per; __syncthreads();
    for (int st = 128; st > 0; st >>= 1) {
        if (threadIdx.x < st) red[threadIdx.x] += red[threadIdx.x+st];
        __syncthreads();
    }
    if (threadIdx.x == 0) atomicAdd(out_loss, red[0] * (1.0f/16.0f));
}

__global__ void unitrepr_kernel(const int* __restrict__ Aarr, const int* __restrict__ posa,
                                const int* __restrict__ Barr,
                                const float* __restrict__ atom_emb, const float* __restrict__ pos_emb,
                                const float* __restrict__ block_emb,
                                const float* __restrict__ h, float* __restrict__ out_ur) {
    #pragma unroll
    for (int k = 0; k < 4; k++) {
        int idx = blockIdx.x*1024 + k*256 + threadIdx.x;
        int u = idx >> 9, c = idx & 511, b = u >> 2;
        out_ur[idx] = atom_emb[Aarr[u]*512+c] + pos_emb[posa[u]*512+c]
                    + block_emb[Barr[b]*512+c] + h[(size_t)b*512+c];
    }
}

extern "C" void kernel_launch(void* const* d_in, const int* in_sizes, int n_in,
                              void* d_out, int out_size, void* d_ws, size_t ws_size,
                              hipStream_t stream) {
    const float* Z         = (const float*)d_in[0];
    const int*   B         = (const int*)d_in[1];
    const int*   A         = (const int*)d_in[2];
    const int*   ap        = (const int*)d_in[3];
    const int*   seg       = (const int*)d_in[6];
    const float* noise     = (const float*)d_in[7];
    const int*   nl        = (const int*)d_in[8];
    const float* sig       = (const float*)d_in[9];
    const float* atom_emb  = (const float*)d_in[10];
    const float* pos_emb   = (const float*)d_in[11];
    const float* block_emb = (const float*)d_in[12];
    const float* edge_emb  = (const float*)d_in[13];
    const float* Wm        = (const float*)d_in[14];
    const float* We        = (const float*)d_in[15];
    const float* Wu        = (const float*)d_in[16];
    const float* wz        = (const float*)d_in[17];
    const float* W1        = (const float*)d_in[18];
    const float* b1        = (const float*)d_in[19];
    const float* W2        = (const float*)d_in[20];
    (void)in_sizes; (void)n_in; (void)d_ws; (void)ws_size; (void)out_size;

    float* out = (float*)d_out;
    const size_t o1 = 8, o2 = 98312, o3 = 16875528, o4 = 21069832, o5 = 21073928;
    float* out_e    = out;
    float* out_pn   = out + o1;
    float* out_ur   = out + o2;
    float* hf       = out + o3;   // block_repr == final h (fp32), updated in place
    float* out_gr   = out + o4;
    float* out_loss = out + o5;

    // scratch arena inside the unit_repr output region (67 MB); unit_repr written last
    char* arena = (char*)(out + o2);
    float* P    = (float*)(arena);                 // 16 MB
    bf16*  msum = (bf16*)(arena + 16777216);       // 8 MB
    bf16*  sh   = (bf16*)(arena + 25165824);       // 8 MB
    bf16*  hb   = (bf16*)(arena + 33554432);       // 8 MB
    float* Zp   = (float*)(arena + 41943040);
    float* Zb0  = (float*)(arena + 42336256);
    float* Zb   = (float*)(arena + 42434560);
    float* zacc = (float*)(arena + 42532864);
    int*   nbr  = (int*)  (arena + 42631168);
    bf16*  WmT  = (bf16*) (arena + 43220992);
    bf16*  WuT  = (bf16*) (arena + 44793856);
    bf16*  W1T  = (bf16*) (arena + 46366720);
    float* ebias= (float*)(arena + 46891008);
    float* eblk = (float*)(arena + 46903296);

    hipMemsetAsync(out_loss, 0, 4, stream);
    hipMemsetAsync(out_gr, 0, 8*512*4, stream);
    hipMemsetAsync(eblk, 0, NB_*4, stream);
    transpose_weights<<<dim3(16,16,7), dim3(32,8), 0, stream>>>(Wm, Wu, W1, WmT, WuT, W1T);
    ebias_kernel<<<12, 256, 0, stream>>>(edge_emb, We, ebias);
    setup_kernel<<<8192, 128, 0, stream>>>(Z, noise, nl, sig, A, ap, B,
                                           atom_emb, pos_emb, block_emb,
                                           Zp, Zb0, Zb, hf, hb);
    knn_kernel<<<2048, 256, 0, stream>>>(Zp, seg, nbr);
    for (int l = 0; l < 3; l++) {
        gemm_kernel<<<512, 256, 0, stream>>>(hb, WmT + (size_t)l*262144, P,
                                             nullptr, nullptr, nullptr, nullptr, nullptr, nullptr, 0);
        edge_kernel<<<8192, 256, 0, stream>>>(P, ebias + l*1024, wz + l*512, Zb, nbr, msum, zacc);
        gemm_kernel<<<512, 256, 0, stream>>>(msum, WuT + (size_t)l*262144, nullptr,
                                             hf, hb, (l == 2) ? sh : nullptr, nullptr, nullptr, nullptr, 1);
        zb_apply<<<96, 256, 0, stream>>>(Zb, zacc);
    }
    gemm_kernel<<<512, 256, 0, stream>>>(sh, W1T, nullptr, nullptr, nullptr, nullptr,
                                         b1, W2, eblk, 2);
    energy_kernel<<<8, 256, 0, stream>>>(eblk, out_e);
    graphrepr_kernel<<<256, 256, 0, stream>>>(hf, out_gr);
    prednoise_loss_kernel<<<128, 256, 0, stream>>>(Zb, Zb0, noise, out_pn, out_loss);
    // unit_repr last: overwrites the scratch arena
    unitrepr_kernel<<<16384, 256, 0, stream>>>(A, ap, B, atom_emb, pos_emb, block_emb, hf, out_ur);
}

// Round 3
// 485.074 us; speedup vs baseline: 1.3062x; 1.0904x over previous
//
#include <hip/hip_runtime.h>
#include <hip/hip_bf16.h>

typedef __bf16 bf16;
typedef __bf16 bf16x2 __attribute__((ext_vector_type(2)));
typedef __bf16 bf16x8 __attribute__((ext_vector_type(8)));
typedef float floatx4 __attribute__((ext_vector_type(4)));

#define NB_ 8192
#define NU_ 32768

__device__ __forceinline__ float silu_f(float x) {
    float e = __expf(-x);
    return x * __builtin_amdgcn_rcpf(1.0f + e);
}

__device__ __forceinline__ float2 unpack_bf2(unsigned v) {
    float2 r;
    r.x = __uint_as_float(v << 16);
    r.y = __uint_as_float(v & 0xFFFF0000u);
    return r;
}

// async global -> LDS, 16B per lane; lds dest = base + lane*16 (HW rule)
__device__ __forceinline__ void gll16(const bf16* g, bf16* l) {
    __builtin_amdgcn_global_load_lds((const __attribute__((address_space(1))) void*)g,
                                     (__attribute__((address_space(3))) void*)l, 16, 0, 0);
}

// =================== init: setup + weight transpose + ebias + zeroing ===================
__global__ __launch_bounds__(256) void init_kernel(
    const float* __restrict__ Z, const float* __restrict__ noise,
    const int* __restrict__ nl, const float* __restrict__ sig,
    const int* __restrict__ Aarr, const int* __restrict__ posa, const int* __restrict__ Barr,
    const float* __restrict__ atom_emb, const float* __restrict__ pos_emb,
    const float* __restrict__ block_emb,
    const float* __restrict__ edge_emb, const float* __restrict__ We,
    const float* __restrict__ Wm, const float* __restrict__ Wu, const float* __restrict__ W1,
    float* __restrict__ Zp, float* __restrict__ Zb0, float* __restrict__ Zb,
    float* __restrict__ hf, bf16* __restrict__ hb,
    bf16* __restrict__ WmT, bf16* __restrict__ WuT, bf16* __restrict__ W1T,
    float* __restrict__ ebias,
    float* __restrict__ out_gr, float* __restrict__ eblk, float* __restrict__ out_loss)
{
    __shared__ float zsh[12];
    __shared__ float tile[32][33];
    int bid = blockIdx.x, tid = threadIdx.x;
    if (bid < 8192) {
        int b = bid, g = b >> 10;
        if (tid < 12) {
            float sg = sig[nl[g]];
            int idx = b*12 + tid;
            float zp = Z[idx] + noise[idx]*sg;
            Zp[idx] = zp;
            zsh[tid] = zp;
        }
        __syncthreads();
        if (tid < 3) {
            float v = 0.25f*(zsh[tid] + zsh[3+tid] + zsh[6+tid] + zsh[9+tid]);
            Zb0[b*3+tid] = v; Zb[b*3+tid] = v;
        }
        int ai[4], pi[4];
        #pragma unroll
        for (int a = 0; a < 4; a++) { ai[a] = Aarr[b*4+a]*512; pi[a] = posa[b*4+a]*512; }
        int bb = Barr[b]*512;
        #pragma unroll
        for (int cc = 0; cc < 2; cc++) {
            int c = tid + cc*256;
            float s = 0.0f;
            #pragma unroll
            for (int a = 0; a < 4; a++) s += atom_emb[ai[a]+c] + pos_emb[pi[a]+c];
            s = 0.25f*s + block_emb[bb+c];
            hf[(size_t)b*512+c] = s;
            hb[(size_t)b*512+c] = (bf16)s;
        }
        return;
    }
    bid -= 8192;
    if (bid < 1792) {   // 7 matrices x 256 tiles (16x16 of 32x32)
        int z = bid >> 8, rem = bid & 255;
        int bx = rem & 15, by = rem >> 4;
        int tx = tid & 31, ty = tid >> 5;     // 32 x 8
        const float* src; bf16* dst;
        if (z < 3)      { src = Wm + (size_t)z*262144;     dst = WmT + (size_t)z*262144; }
        else if (z < 6) { src = Wu + (size_t)(z-3)*262144; dst = WuT + (size_t)(z-3)*262144; }
        else            { src = W1;                        dst = W1T; }
        #pragma unroll
        for (int i = 0; i < 32; i += 8)
            tile[ty+i][tx] = src[(size_t)(by*32+ty+i)*512 + bx*32+tx];
        __syncthreads();
        #pragma unroll
        for (int i = 0; i < 32; i += 8)
            dst[(size_t)(bx*32+ty+i)*512 + by*32+tx] = (bf16)tile[tx][ty+i];
        return;
    }
    bid -= 1792;
    if (bid < 12) {
        int gid = bid*256 + tid;
        int l = gid >> 10, t = (gid >> 9) & 1, c = gid & 511;
        float s = 0.0f;
        #pragma unroll 8
        for (int e = 0; e < 64; e++)
            s += edge_emb[t*64 + e] * We[(size_t)(l*64 + e)*512 + c];
        ebias[gid] = s;
        return;
    }
    bid -= 12;
    int k = bid*256 + tid;
    if (k < 4096) out_gr[k] = 0.0f;
    else if (k < 12288) eblk[k-4096] = 0.0f;
    else if (k == 12288) out_loss[0] = 0.0f;
}

// =================== KNN body: one wave per dst block ===================
__device__ void knn_body(int kb, const float* __restrict__ Zp, const int* __restrict__ seg,
                         int* __restrict__ nbr) {
    int wid = threadIdx.x >> 6;
    int lane = threadIdx.x & 63;
    int r = ((kb & 7) << 10) + ((kb >> 3) << 2) + wid;   // XCD-local graph
    int g = r >> 10;
    int il = r & 1023;
    int base = g << 10;
    int segr = seg[r];
    float za[4][3];
    #pragma unroll
    for (int a = 0; a < 4; a++)
        #pragma unroll
        for (int d = 0; d < 3; d++)
            za[a][d] = Zp[r*12 + a*3 + d];
    float dist[16];
    unsigned smask = 0;
    #pragma unroll
    for (int t = 0; t < 16; t++) {
        int jb = base + t*64 + lane;
        const float4* p = (const float4*)(Zp + (size_t)jb*12);
        float4 v0 = p[0], v1 = p[1], v2 = p[2];
        float bx[4] = {v0.x, v0.w, v1.z, v2.y};
        float by[4] = {v0.y, v1.x, v1.w, v2.z};
        float bz[4] = {v0.z, v1.y, v2.x, v2.w};
        float dm = 3.0e38f;
        #pragma unroll
        for (int a = 0; a < 4; a++) {
            #pragma unroll
            for (int bq = 0; bq < 4; bq++) {
                float dx = za[a][0]-bx[bq], dy = za[a][1]-by[bq], dz = za[a][2]-bz[bq];
                dm = fminf(dm, dx*dx + dy*dy + dz*dz);
            }
        }
        dist[t] = dm;
        if (seg[jb] == segr) smask |= (1u << t);
    }
    const float INF = 3.0e38f;
    for (int phase = 0; phase < 2; phase++) {
        float wd[16];
        #pragma unroll
        for (int t = 0; t < 16; t++) {
            bool ok = (phase == 0) ? (((smask >> t) & 1u) && (t*64 + lane != il))
                                   : (!((smask >> t) & 1u));
            wd[t] = ok ? dist[t] : INF;
        }
        for (int it = 0; it < 9; it++) {
            float bd = wd[0]; int bt = 0;
            #pragma unroll
            for (int t = 1; t < 16; t++) { if (wd[t] < bd) { bd = wd[t]; bt = t; } }
            float mv = bd;
            #pragma unroll
            for (int off = 32; off >= 1; off >>= 1) mv = fminf(mv, __shfl_xor(mv, off, 64));
            unsigned long long msk = __ballot(bd == mv);
            int wl = __ffsll(msk) - 1;
            int wt = __shfl(bt, wl, 64);
            if (lane == 0) nbr[r*18 + phase*9 + it] = base + wt*64 + wl;
            bool amwin = (lane == wl);
            #pragma unroll
            for (int t = 0; t < 16; t++) if (amwin && t == wt) wd[t] = INF;
        }
    }
}

// =================== bf16 MFMA GEMM body: [8192,512] @ BT^T, tile 128x64, BK=32 ===================
// global_load_lds staging with XOR chunk swizzle (qt ^= (row>>1)&3) -> conflict-free unpadded LDS
// mode 0: Pb = bf16(acc)
// mode 1: hf += silu(acc); hb = bf16(hf); if shp: shp = bf16(silu(hf)); nt==0 tiles also apply Zb += zacc/18
// mode 2: t = silu(acc + b1[col]); eblk[row] += t . W2
__device__ void gemm_body(const bf16* __restrict__ A, const bf16* __restrict__ BT,
                          bf16* __restrict__ Pb, float* __restrict__ hf,
                          bf16* __restrict__ hb, bf16* __restrict__ shp,
                          const float* __restrict__ b1, const float* __restrict__ W2,
                          float* __restrict__ eblk,
                          float* __restrict__ Zb, const float* __restrict__ zacc,
                          int mode, int bid)
{
    __shared__ alignas(16) bf16 sA[128*32];
    __shared__ alignas(16) bf16 sB[64*32];
    int mt = bid & 63, nt = bid >> 6;
    int m0 = mt*128, n0 = nt*64;
    int tid = threadIdx.x, lane = tid & 63, w = tid >> 6;
    int wm = w & 1, wn = w >> 1;
    int lm = lane & 15, q = lane >> 4;

    // staging: physical chunk p holds logical chunk (row=p>>2, qt=(p&3)^((row>>1)&3))
    int pA0 = w*128 + lane, pA1 = pA0 + 64, pB = w*64 + lane;
    int rA0 = pA0 >> 2, qA0 = (pA0 & 3) ^ ((rA0 >> 1) & 3);
    int rA1 = pA1 >> 2, qA1 = (pA1 & 3) ^ ((rA1 >> 1) & 3);
    int rB  = pB  >> 2, qB  = (pB  & 3) ^ ((rB  >> 1) & 3);
    const bf16* gA0 = A  + (size_t)(m0 + rA0)*512 + qA0*8;
    const bf16* gA1 = A  + (size_t)(m0 + rA1)*512 + qA1*8;
    const bf16* gB  = BT + (size_t)(n0 + rB )*512 + qB*8;
    bf16* lA0 = sA + (w*128)*8;
    bf16* lA1 = sA + (w*128 + 64)*8;
    bf16* lB  = sB + (w*64)*8;

    // fragment read addresses (swizzle depends only on lm)
    int swq = (q ^ ((lm >> 1) & 3)) * 8;
    const bf16* pa[4]; const bf16* pb2[2];
    #pragma unroll
    for (int tm = 0; tm < 4; tm++) pa[tm] = sA + (wm*64 + tm*16 + lm)*32 + swq;
    #pragma unroll
    for (int tn = 0; tn < 2; tn++) pb2[tn] = sB + (wn*32 + tn*16 + lm)*32 + swq;

    floatx4 zv = {0.0f, 0.0f, 0.0f, 0.0f};
    floatx4 acc[4][2];
    #pragma unroll
    for (int i = 0; i < 4; i++)
        #pragma unroll
        for (int j = 0; j < 2; j++) acc[i][j] = zv;

    for (int k0 = 0; k0 < 512; k0 += 32) {
        gll16(gA0 + k0, lA0);
        gll16(gA1 + k0, lA1);
        gll16(gB  + k0, lB);
        __syncthreads();
        bf16x8 af[4], bfr[2];
        #pragma unroll
        for (int tm = 0; tm < 4; tm++) af[tm] = *(const bf16x8*)pa[tm];
        #pragma unroll
        for (int tn = 0; tn < 2; tn++) bfr[tn] = *(const bf16x8*)pb2[tn];
        #pragma unroll
        for (int tm = 0; tm < 4; tm++)
            #pragma unroll
            for (int tn = 0; tn < 2; tn++)
                acc[tm][tn] = __builtin_amdgcn_mfma_f32_16x16x32_bf16(af[tm], bfr[tn], acc[tm][tn], 0, 0, 0);
        __syncthreads();
    }

    if (mode == 1 && nt == 0) {       // fold zb_apply: rows m0..m0+127
        int o = m0*3 + tid;
        Zb[o] += zacc[o] * (1.0f/18.0f);
        if (tid < 128) {
            int o2 = m0*3 + 256 + tid;
            Zb[o2] += zacc[o2] * (1.0f/18.0f);
        }
    }

    if (mode == 2) {
        #pragma unroll
        for (int tm = 0; tm < 4; tm++) {
            #pragma unroll
            for (int rr = 0; rr < 4; rr++) {
                float part = 0.0f;
                #pragma unroll
                for (int tn = 0; tn < 2; tn++) {
                    int col = n0 + wn*32 + tn*16 + lm;
                    float t = silu_f(acc[tm][tn][rr] + b1[col]);
                    part += t * W2[col];
                }
                part += __shfl_xor(part, 1, 64);
                part += __shfl_xor(part, 2, 64);
                part += __shfl_xor(part, 4, 64);
                part += __shfl_xor(part, 8, 64);
                if (lm == 0) {
                    int row = m0 + wm*64 + tm*16 + q*4 + rr;
                    atomicAdd(&eblk[row], part);
                }
            }
        }
        return;
    }
    #pragma unroll
    for (int tm = 0; tm < 4; tm++) {
        #pragma unroll
        for (int tn = 0; tn < 2; tn++) {
            #pragma unroll
            for (int rr = 0; rr < 4; rr++) {
                int row = m0 + wm*64 + tm*16 + q*4 + rr;
                int col = n0 + wn*32 + tn*16 + lm;
                size_t o = (size_t)row*512 + col;
                float v = acc[tm][tn][rr];
                if (mode == 0) {
                    Pb[o] = (bf16)v;
                } else {
                    float nh = hf[o] + silu_f(v);
                    hf[o] = nh;
                    hb[o] = (bf16)nh;
                    if (shp) shp[o] = (bf16)silu_f(nh);
                }
            }
        }
    }
}

__global__ __launch_bounds__(256) void gemm_kernel(const bf16* __restrict__ A, const bf16* __restrict__ BT,
                                                   bf16* __restrict__ Pb, float* __restrict__ hf,
                                                   bf16* __restrict__ hb, bf16* __restrict__ shp,
                                                   const float* __restrict__ b1, const float* __restrict__ W2,
                                                   float* __restrict__ eblk,
                                                   float* __restrict__ Zb, const float* __restrict__ zacc,
                                                   int mode) {
    gemm_body(A, BT, Pb, hf, hb, shp, b1, W2, eblk, Zb, zacc, mode, blockIdx.x);
}

// fused: blocks [0,512) run P-GEMM layer 0; blocks [512, 2560) run KNN
__global__ __launch_bounds__(256) void knn_pgemm0_kernel(const bf16* __restrict__ hb,
                                                         const bf16* __restrict__ WmT0,
                                                         bf16* __restrict__ Pb,
                                                         const float* __restrict__ Zp,
                                                         const int* __restrict__ seg,
                                                         int* __restrict__ nbr) {
    if (blockIdx.x < 512)
        gemm_body(hb, WmT0, Pb, nullptr, nullptr, nullptr, nullptr, nullptr, nullptr,
                  nullptr, nullptr, 0, blockIdx.x);
    else
        knn_body(blockIdx.x - 512, Zp, seg, nbr);
}

// =================== edge aggregation (bf16 P) ===================
__global__ __launch_bounds__(256) void edge_kernel(const bf16* __restrict__ Pb, const float* __restrict__ ebias,
                                                   const float* __restrict__ wz, const float* __restrict__ Zb,
                                                   const int* __restrict__ nbr, bf16* __restrict__ msum,
                                                   float* __restrict__ zacc) {
    int bid = blockIdx.x, tid = threadIdx.x;
    int b = ((bid & 7) << 10) | (bid >> 3);      // XCD-local graph for L2 reuse of Pb slice
    int c0 = 2*tid;
    int lane = tid & 63, wid = tid >> 6;
    __shared__ int srcs[18];
    __shared__ float red[18][4];
    __shared__ float term[18][3];
    if (tid < 18) srcs[tid] = nbr[b*18 + tid];
    __syncthreads();
    float2 pd  = unpack_bf2(*(const unsigned*)(Pb + (size_t)b*512 + c0));
    float2 eb0 = *(const float2*)(ebias + c0);
    float2 eb1 = *(const float2*)(ebias + 512 + c0);
    float2 w   = *(const float2*)(wz + c0);
    float ms0 = 0.0f, ms1 = 0.0f;
    float pdot[18];
    #pragma unroll
    for (int e = 0; e < 18; e++) {
        int s = srcs[e];
        float2 pv = unpack_bf2(*(const unsigned*)(Pb + (size_t)s*512 + c0));
        float ba = (e < 9) ? eb0.x : eb1.x;
        float bb = (e < 9) ? eb0.y : eb1.y;
        float m0 = silu_f(pv.x + pd.x + ba);
        float m1 = silu_f(pv.y + pd.y + bb);
        ms0 += m0; ms1 += m1;
        pdot[e] = m0*w.x + m1*w.y;
    }
    bf16x2 mp = { (bf16)ms0, (bf16)ms1 };
    *(bf16x2*)(msum + (size_t)b*512 + c0) = mp;
    #pragma unroll
    for (int e = 0; e < 18; e++) {
        float v = pdot[e];
        #pragma unroll
        for (int off = 32; off >= 1; off >>= 1) v += __shfl_xor(v, off, 64);
        if (lane == 0) red[e][wid] = v;
    }
    __syncthreads();
    if (tid < 18) {
        float dot = red[tid][0] + red[tid][1] + red[tid][2] + red[tid][3];
        float coef = tanhf(dot);
        int s = srcs[tid];
        #pragma unroll
        for (int d = 0; d < 3; d++)
            term[tid][d] = (Zb[s*3 + d] - Zb[b*3 + d]) * coef;
    }
    __syncthreads();
    if (tid < 3) {
        float s = 0.0f;
        #pragma unroll
        for (int e = 0; e < 18; e++) s += term[e][tid];
        zacc[b*3 + tid] = s;
    }
}

// =================== finalize: energy + graph_repr + pred_noise/loss ===================
__global__ __launch_bounds__(256) void finalize_kernel(const float* __restrict__ eblk, float* __restrict__ out_e,
                                                       const float* __restrict__ hf, float* __restrict__ out_gr,
                                                       const float* __restrict__ Zb, const float* __restrict__ Zb0,
                                                       const float* __restrict__ noise,
                                                       float* __restrict__ out_pn, float* __restrict__ out_loss) {
    __shared__ float red[256];
    int bid = blockIdx.x, tid = threadIdx.x;
    if (bid < 8) {
        int g = bid;
        float s = 0.0f;
        #pragma unroll
        for (int k = 0; k < 4; k++) s += eblk[g*1024 + k*256 + tid];
        red[tid] = s; __syncthreads();
        for (int st = 128; st > 0; st >>= 1) {
            if (tid < st) red[tid] += red[tid+st];
            __syncthreads();
        }
        if (tid == 0) out_e[g] = red[0];
        return;
    }
    if (bid < 136) {
        int u = (bid-8)*256 + tid;
        int b = u >> 2;
        float per = 0.0f;
        #pragma unroll
        for (int d = 0; d < 3; d++) {
            float dv = Zb[b*3+d] - Zb0[b*3+d];
            out_pn[u*3+d] = dv;
            float e = dv - noise[u*3+d];
            per += e*e;
        }
        red[tid] = per; __syncthreads();
        for (int st = 128; st > 0; st >>= 1) {
            if (tid < st) red[tid] += red[tid+st];
            __syncthreads();
        }
        if (tid == 0) atomicAdd(out_loss, red[0] * (1.0f/16.0f));
        return;
    }
    int pid = bid - 136;                // 256 partial blocks
    int g = pid >> 5;
    int rc = (pid >> 1) & 15;
    int ch = pid & 1;
    int c = ch*256 + tid;
    int b0 = (g << 10) + rc*64;
    float s = 0.0f;
    for (int i = 0; i < 64; i++) s += hf[(size_t)(b0+i)*512 + c];
    atomicAdd(&out_gr[g*512 + c], s);
}

// =================== unit_repr (float4) ===================
__global__ __launch_bounds__(256) void unitrepr_kernel(const int* __restrict__ Aarr, const int* __restrict__ posa,
                                                       const int* __restrict__ Barr,
                                                       const float* __restrict__ atom_emb, const float* __restrict__ pos_emb,
                                                       const float* __restrict__ block_emb,
                                                       const float* __restrict__ hf, float* __restrict__ out_ur) {
    int gid = blockIdx.x*256 + threadIdx.x;      // 32768 units x 128 threads
    int u = gid >> 7, c = (gid & 127) << 2, b = u >> 2;
    float4 va = *(const float4*)(atom_emb + (size_t)Aarr[u]*512 + c);
    float4 vp = *(const float4*)(pos_emb + (size_t)posa[u]*512 + c);
    float4 vb = *(const float4*)(block_emb + (size_t)Barr[b]*512 + c);
    float4 vh = *(const float4*)(hf + (size_t)b*512 + c);
    float4 o;
    o.x = va.x + vp.x + vb.x + vh.x;
    o.y = va.y + vp.y + vb.y + vh.y;
    o.z = va.z + vp.z + vb.z + vh.z;
    o.w = va.w + vp.w + vb.w + vh.w;
    *(float4*)(out_ur + (size_t)u*512 + c) = o;
}

extern "C" void kernel_launch(void* const* d_in, const int* in_sizes, int n_in,
                              void* d_out, int out_size, void* d_ws, size_t ws_size,
                              hipStream_t stream) {
    const float* Z         = (const float*)d_in[0];
    const int*   B         = (const int*)d_in[1];
    const int*   A         = (const int*)d_in[2];
    const int*   ap        = (const int*)d_in[3];
    const int*   seg       = (const int*)d_in[6];
    const float* noise     = (const float*)d_in[7];
    const int*   nl        = (const int*)d_in[8];
    const float* sig       = (const float*)d_in[9];
    const float* atom_emb  = (const float*)d_in[10];
    const float* pos_emb   = (const float*)d_in[11];
    const float* block_emb = (const float*)d_in[12];
    const float* edge_emb  = (const float*)d_in[13];
    const float* Wm        = (const float*)d_in[14];
    const float* We        = (const float*)d_in[15];
    const float* Wu        = (const float*)d_in[16];
    const float* wz        = (const float*)d_in[17];
    const float* W1        = (const float*)d_in[18];
    const float* b1        = (const float*)d_in[19];
    const float* W2        = (const float*)d_in[20];
    (void)in_sizes; (void)n_in; (void)d_ws; (void)ws_size; (void)out_size;

    float* out = (float*)d_out;
    const size_t o1 = 8, o2 = 98312, o3 = 16875528, o4 = 21069832, o5 = 21073928;
    float* out_e    = out;
    float* out_pn   = out + o1;
    float* out_ur   = out + o2;
    float* hf       = out + o3;   // block_repr == final h (fp32), updated in place
    float* out_gr   = out + o4;
    float* out_loss = out + o5;

    // scratch arena inside the unit_repr output region (67 MB); unit_repr written last
    char* arena = (char*)(out + o2);
    bf16*  Pb   = (bf16*)(arena);                  // 8 MB
    bf16*  msum = (bf16*)(arena + 16777216);       // 8 MB
    bf16*  sh   = (bf16*)(arena + 25165824);       // 8 MB
    bf16*  hb   = (bf16*)(arena + 33554432);       // 8 MB
    float* Zp   = (float*)(arena + 41943040);
    float* Zb0  = (float*)(arena + 42336256);
    float* Zb   = (float*)(arena + 42434560);
    float* zacc = (float*)(arena + 42532864);
    int*   nbr  = (int*)  (arena + 42631168);
    bf16*  WmT  = (bf16*) (arena + 43220992);
    bf16*  WuT  = (bf16*) (arena + 44793856);
    bf16*  W1T  = (bf16*) (arena + 46366720);
    float* ebias= (float*)(arena + 46891008);
    float* eblk = (float*)(arena + 46903296);

    init_kernel<<<8192 + 1792 + 12 + 49, 256, 0, stream>>>(
        Z, noise, nl, sig, A, ap, B, atom_emb, pos_emb, block_emb,
        edge_emb, We, Wm, Wu, W1,
        Zp, Zb0, Zb, hf, hb, WmT, WuT, W1T, ebias, out_gr, eblk, out_loss);

    knn_pgemm0_kernel<<<512 + 2048, 256, 0, stream>>>(hb, WmT, Pb, Zp, seg, nbr);

    for (int l = 0; l < 3; l++) {
        if (l > 0)
            gemm_kernel<<<512, 256, 0, stream>>>(hb, WmT + (size_t)l*262144, Pb,
                                                 nullptr, nullptr, nullptr, nullptr, nullptr, nullptr,
                                                 nullptr, nullptr, 0);
        edge_kernel<<<8192, 256, 0, stream>>>(Pb, ebias + l*1024, wz + l*512, Zb, nbr, msum, zacc);
        gemm_kernel<<<512, 256, 0, stream>>>(msum, WuT + (size_t)l*262144, nullptr,
                                             hf, hb, (l == 2) ? sh : nullptr, nullptr, nullptr, nullptr,
                                             Zb, zacc, 1);
    }
    gemm_kernel<<<512, 256, 0, stream>>>(sh, W1T, nullptr, nullptr, nullptr, nullptr,
                                         b1, W2, eblk, nullptr, nullptr, 2);
    finalize_kernel<<<392, 256, 0, stream>>>(eblk, out_e, hf, out_gr, Zb, Zb0, noise, out_pn, out_loss);
    // unit_repr last: overwrites the scratch arena
    unitrepr_kernel<<<16384, 256, 0, stream>>>(A, ap, B, atom_emb, pos_emb, block_emb, hf, out_ur);
}